// Round 9
// baseline (562.978 us; speedup 1.0000x reference)
//
#include <hip/hip_runtime.h>
#include <hip/hip_bf16.h>
#include <stdint.h>

// ---------------------------------------------------------------------------
// CrossAttention: out = softmax((X Wq)(K Wk)^T * s) (V Wv) Wo  (+biases)
// B=4, Nq=4096, Nk=1024, QUERY_DIM=1024, KEY_DIM=768, H=16, HD=64
// R13: fix R12's permlane operand order. LLVM gfx950 semantics:
//      permlane32_swap(first,second): first[32:63] <-> second[0:31];
//      permlane16_swap: first[16:31,48:63] <-> second[0:15,32:47].
//      Network (quarters): A=[E0..E3],B=[F0..F3]; P32(A,B)->A=[E0,E1,F0,F1],
//      B=[E2,E3,F2,F3]; P16(A,B)->A=[E0,E2,F0,F2]=D0, B=[E1,E3,F1,F3]=D2.
//      R12 passed (B,A) -> scrambled P (absmax 0.37). Only the 4 asm lines
//      changed vs R12.
// Carried (R12): in-register P (no P_lds), LDS 40KB, V 3-buf, attn XCD
//      swizzle; XCD swizzle + 3-buffer counted-vmcnt 128x256 GEMM, fused
//      conversions/transposes, deferred-PV pipeline, raw v_exp_f32,
//      XOR-swizzled LDS, no-max exp2 softmax, MFMA row-sum, fused K/V proj.
// ---------------------------------------------------------------------------

typedef unsigned short u16;
typedef __attribute__((ext_vector_type(8))) short short8;   // 8 bf16 = 4 VGPRs
typedef __attribute__((ext_vector_type(4))) float f32x4;    // MFMA C/D frag

#define B_SZ 4
#define NQ   4096
#define NK   1024
#define QDIM 1024
#define KDIM 768
#define NH   16
#define HD   64
// scale * log2(e): softmax computed in exp2 domain (folded into Q projection)
#define QSCALE (0.125f * 1.44269504f)

__device__ __forceinline__ u16 f2bf(float f) {
  union { float f; uint32_t u; } v; v.f = f;
  uint32_t u = v.u;
  return (u16)((u + 0x7FFFu + ((u >> 16) & 1u)) >> 16);  // RNE
}

// packed f32x2 -> bf16x2 (v_cvt_pk_bf16_f32 on gfx950)
__device__ __forceinline__ uint32_t pk2(float a, float b) {
  union { __hip_bfloat162 h; uint32_t u; } cv;
  cv.h = __float22bfloat162_rn(float2{a, b});
  return cv.u;
}

// raw v_exp_f32 (no denormal-guard expansion; underflow flushes to 0 - fine
// for softmax numerator)
__device__ __forceinline__ float fexp2(float x) {
  return __builtin_amdgcn_exp2f(x);
}

// global -> LDS async copy, 16B per lane; lds base must be wave-uniform.
__device__ __forceinline__ void async16(u16* lds, const u16* g) {
  __builtin_amdgcn_global_load_lds(
      (__attribute__((address_space(1))) void*)(g),
      (__attribute__((address_space(3))) void*)(lds), 16, 0, 0);
}

// ---------------------------------------------------------------------------
// fused fp32 -> bf16 for query/key/value (range-partitioned single launch)
// ---------------------------------------------------------------------------
__global__ __launch_bounds__(256) void f32_to_bf16_all(const float* __restrict__ q,
                                                       const float* __restrict__ k,
                                                       const float* __restrict__ v,
                                                       u16* __restrict__ oq,
                                                       u16* __restrict__ ok,
                                                       u16* __restrict__ ov,
                                                       int n4q, int n4kv) {
  int i = blockIdx.x * 256 + threadIdx.x;
  const float* in; u16* out; int idx;
  if (i < n4q) { in = q; out = oq; idx = i; }
  else if (i < n4q + n4kv) { in = k; out = ok; idx = i - n4q; }
  else if (i < n4q + 2 * n4kv) { in = v; out = ov; idx = i - n4q - n4kv; }
  else return;
  f32x4 vv = ((const f32x4*)in)[idx];
  uint2 o = {pk2(vv.x, vv.y), pk2(vv.z, vv.w)};
  ((uint2*)out)[idx] = o;
}

// ---------------------------------------------------------------------------
// fused weight transposes: z selects {Wq, Wk, Wv, Wo}; K in {1024,768,768,1024}
// W (K x N fp32, row-major) -> Wt (N x K bf16, row-major)   [LDS-tiled]
// ---------------------------------------------------------------------------
__global__ __launch_bounds__(256) void transpose4_k(const float* __restrict__ W0,
                                                    const float* __restrict__ W1,
                                                    const float* __restrict__ W2,
                                                    const float* __restrict__ W3,
                                                    u16* __restrict__ T0,
                                                    u16* __restrict__ T1,
                                                    u16* __restrict__ T2,
                                                    u16* __restrict__ T3) {
  const int z = blockIdx.z;
  const float* W = (z == 0) ? W0 : (z == 1) ? W1 : (z == 2) ? W2 : W3;
  u16* T = (z == 0) ? T0 : (z == 1) ? T1 : (z == 2) ? T2 : T3;
  const int K = (z == 1 || z == 2) ? KDIM : QDIM;
  const int N = QDIM;
  int nb = blockIdx.x * 32, kb = blockIdx.y * 32;
  if (kb >= K) return;  // block-uniform exit (before barrier)
  __shared__ float t[32][33];
  int tx = threadIdx.x & 31, ty = threadIdx.x >> 5;  // 32 x 8
#pragma unroll
  for (int i = 0; i < 4; ++i)
    t[ty + i * 8][tx] = W[(size_t)(kb + ty + i * 8) * N + nb + tx];
  __syncthreads();
#pragma unroll
  for (int i = 0; i < 4; ++i)
    T[(size_t)(nb + ty + i * 8) * K + kb + tx] = f2bf(t[tx][ty + i * 8]);
}

// ---------------------------------------------------------------------------
// C[M,N] = (A[M,K] * Bt[N,K]^T + bias) * scale ; out bf16 or fp32
// 128x256 tile, BK=64, 512 threads (8 waves: 2M x 4N, each 64x64 out).
// 3 LDS K-tile buffers, staging 2 K-tiles ahead, counted vmcnt(6).
// 1D grid + XCD-chunked swizzle; N-panel fastest in work decode so each
// XCD reuses one A row-block across all N/256 panels via its L2.
// Requires gridDim.x % 8 == 0, K >= 128, K%64==0.
// ---------------------------------------------------------------------------
__global__ __launch_bounds__(512, 2) void gemm_bt256(const u16* __restrict__ A,
                                                     const u16* __restrict__ Bt,
                                                     const float* __restrict__ bias,
                                                     float* __restrict__ Cf,
                                                     u16* __restrict__ Cb,
                                                     int M, int N, int K,
                                                     int out_bf16, float scale) {
  __shared__ __align__(16) u16 Al[3][128 * 64];
  __shared__ __align__(16) u16 Bl[3][256 * 64];
  const int tid = threadIdx.x;
  const int w = tid >> 6, lane = tid & 63;
  const int g = lane >> 4, l15 = lane & 15;
  const int sw = l15 & 7;
  const int bid = blockIdx.x;
  const int cpx = gridDim.x >> 3;
  const int swz = (bid & 7) * cpx + (bid >> 3);
  const int nby = N >> 8;
  const int mbase = (swz / nby) * 128, nbase = (swz % nby) * 256;
  const int wm = (w & 1) * 64, wn = (w >> 1) * 64;
  const int NT = K >> 6;

  // ---- staging lane constants ----
  const int ca0 = 0 * 512 + tid, ca1 = 1 * 512 + tid;
  const int ra0 = ca0 >> 3, rc0 = ((ca0 & 7) ^ (ra0 & 7)) * 8;
  const int ra1 = ca1 >> 3, rc1 = ((ca1 & 7) ^ (ra1 & 7)) * 8;
  const u16* pa0 = A + (size_t)(mbase + ra0) * K + rc0;
  const u16* pa1 = A + (size_t)(mbase + ra1) * K + rc1;
  const u16* pb[4];
#pragma unroll
  for (int i = 0; i < 4; ++i) {
    int c = i * 512 + tid;
    int row = c >> 3, col = ((c & 7) ^ (row & 7)) * 8;
    pb[i] = Bt + (size_t)(nbase + row) * K + col;
  }
  const int lA0 = (0 * 512 + w * 64) * 8, lA1 = (1 * 512 + w * 64) * 8;
  int lB[4];
#pragma unroll
  for (int i = 0; i < 4; ++i) lB[i] = (i * 512 + w * 64) * 8;

  f32x4 zero4 = {0.f, 0.f, 0.f, 0.f};
  f32x4 acc[4][4];
#pragma unroll
  for (int i = 0; i < 4; ++i)
#pragma unroll
    for (int j = 0; j < 4; ++j) acc[i][j] = zero4;

  // ---- prologue: stage kt0 -> buf0, kt1 -> buf1 ----
  async16(&Al[0][lA0], pa0); async16(&Al[0][lA1], pa1);
#pragma unroll
  for (int i = 0; i < 4; ++i) async16(&Bl[0][lB[i]], pb[i]);
  pa0 += 64; pa1 += 64;
#pragma unroll
  for (int i = 0; i < 4; ++i) pb[i] += 64;
  async16(&Al[1][lA0], pa0); async16(&Al[1][lA1], pa1);
#pragma unroll
  for (int i = 0; i < 4; ++i) async16(&Bl[1][lB[i]], pb[i]);
  pa0 += 64; pa1 += 64;
#pragma unroll
  for (int i = 0; i < 4; ++i) pb[i] += 64;
  asm volatile("s_waitcnt vmcnt(6)" ::: "memory");  // kt0 landed; kt1 in flight
  __builtin_amdgcn_sched_barrier(0);
  __builtin_amdgcn_s_barrier();

  int cb = 0, sb = 2;
  for (int kt = 0; kt < NT; ++kt) {
    const u16* Ap = &Al[cb][0];
    const u16* Bp = &Bl[cb][0];
    const bool st = (kt + 2 < NT);

    // ---- phase 0: acc[0..3][0..1] ----
    short8 af[4][2], bfa[2][2];
#pragma unroll
    for (int mt = 0; mt < 4; ++mt) {
      af[mt][0] = *(const short8*)&Ap[(wm + mt * 16 + l15) * 64 + (g ^ sw) * 8];
      af[mt][1] = *(const short8*)&Ap[(wm + mt * 16 + l15) * 64 + ((4 + g) ^ sw) * 8];
    }
#pragma unroll
    for (int nt = 0; nt < 2; ++nt) {
      bfa[nt][0] = *(const short8*)&Bp[(wn + nt * 16 + l15) * 64 + (g ^ sw) * 8];
      bfa[nt][1] = *(const short8*)&Bp[(wn + nt * 16 + l15) * 64 + ((4 + g) ^ sw) * 8];
    }
    if (st) {
      async16(&Al[sb][lA0], pa0);
      async16(&Al[sb][lA1], pa1);
      async16(&Bl[sb][lB[0]], pb[0]);
      async16(&Bl[sb][lB[1]], pb[1]);
    }
    __builtin_amdgcn_s_barrier();
    asm volatile("s_waitcnt lgkmcnt(0)" ::: "memory");
    __builtin_amdgcn_sched_barrier(0);
    __builtin_amdgcn_s_setprio(1);
#pragma unroll
    for (int ks = 0; ks < 2; ++ks)
#pragma unroll
      for (int mt = 0; mt < 4; ++mt)
#pragma unroll
        for (int nt = 0; nt < 2; ++nt)
          acc[mt][nt] = __builtin_amdgcn_mfma_f32_16x16x32_bf16(af[mt][ks], bfa[nt][ks],
                                                                acc[mt][nt], 0, 0, 0);
    __builtin_amdgcn_s_setprio(0);
    __builtin_amdgcn_s_barrier();

    // ---- phase 1: acc[0..3][2..3] ----
    short8 bfb[2][2];
#pragma unroll
    for (int nt = 0; nt < 2; ++nt) {
      bfb[nt][0] = *(const short8*)&Bp[(wn + (nt + 2) * 16 + l15) * 64 + (g ^ sw) * 8];
      bfb[nt][1] = *(const short8*)&Bp[(wn + (nt + 2) * 16 + l15) * 64 + ((4 + g) ^ sw) * 8];
    }
    if (st) {
      async16(&Bl[sb][lB[2]], pb[2]);
      async16(&Bl[sb][lB[3]], pb[3]);
      pa0 += 64; pa1 += 64;
#pragma unroll
      for (int i = 0; i < 4; ++i) pb[i] += 64;
    }
    __builtin_amdgcn_s_barrier();
    asm volatile("s_waitcnt lgkmcnt(0)" ::: "memory");
    __builtin_amdgcn_sched_barrier(0);
    __builtin_amdgcn_s_setprio(1);
#pragma unroll
    for (int ks = 0; ks < 2; ++ks)
#pragma unroll
      for (int mt = 0; mt < 4; ++mt)
#pragma unroll
        for (int nt = 0; nt < 2; ++nt)
          acc[mt][nt + 2] = __builtin_amdgcn_mfma_f32_16x16x32_bf16(af[mt][ks], bfb[nt][ks],
                                                                    acc[mt][nt + 2], 0, 0, 0);
    __builtin_amdgcn_s_setprio(0);

    // ---- K-tile boundary: ensure kt+1 landed; kt+2 may stay in flight ----
    if (kt < NT - 2) {
      asm volatile("s_waitcnt vmcnt(6)" ::: "memory");
    } else if (kt == NT - 2) {
      asm volatile("s_waitcnt vmcnt(0)" ::: "memory");
    }
    __builtin_amdgcn_sched_barrier(0);
    __builtin_amdgcn_s_barrier();
    cb = (cb == 2) ? 0 : cb + 1;
    sb = (sb == 2) ? 0 : sb + 1;
  }

  // ---- epilogue ----
#pragma unroll
  for (int nt = 0; nt < 4; ++nt) {
    int col = nbase + wn + nt * 16 + l15;
    float bv = bias[col];
#pragma unroll
    for (int mt = 0; mt < 4; ++mt)
#pragma unroll
      for (int r = 0; r < 4; ++r) {
        int row = mbase + wm + mt * 16 + g * 4 + r;
        float v = (acc[mt][nt][r] + bv) * scale;
        if (out_bf16) Cb[(size_t)row * N + col] = f2bf(v);
        else          Cf[(size_t)row * N + col] = v;
      }
  }
}

// ---------------------------------------------------------------------------
// Combined K/V projection, 1D grid + XCD-chunked swizzle.
// ct==0 -> Kp[M,N] = kA*Wk^T + bk ; ct==1 -> VT[N,M] = (vA*Wv^T + bv)^T
// ---------------------------------------------------------------------------
__global__ __launch_bounds__(256) void gemm_kv(const u16* __restrict__ kA,
                                               const u16* __restrict__ vA,
                                               const u16* __restrict__ Wk,
                                               const u16* __restrict__ Wv,
                                               const float* __restrict__ bk,
                                               const float* __restrict__ bv,
                                               u16* __restrict__ Kp,
                                               u16* __restrict__ VT,
                                               int M, int N, int K) {
  __shared__ __align__(16) u16 Al[128 * 64];
  __shared__ __align__(16) u16 Bl[128 * 64];
  const int bid = blockIdx.x;                     // 512 blocks
  const int swz = (bid & 7) * 64 + (bid >> 3);    // XCD-chunked
  const int ct = swz >> 8;                        // uniform
  const int mbase = (swz & 31) * 128, nbase = ((swz >> 5) & 7) * 128;
  const u16* A  = ct ? vA : kA;
  const u16* Bt = ct ? Wv : Wk;
  const float* bias = ct ? bv : bk;
  const int tid = threadIdx.x;
  const int w = tid >> 6, lane = tid & 63;
  const int g = lane >> 4, l15 = lane & 15;
  const int sw = l15 & 7;
  const int wm = (w & 1) * 64, wn = (w >> 1) * 64;

  f32x4 zero4 = {0.f, 0.f, 0.f, 0.f};
  f32x4 acc[4][4];  // ct=0: [mt][nt]; ct=1: [nt][mt] (transposed D)
#pragma unroll
  for (int i = 0; i < 4; ++i)
#pragma unroll
    for (int j = 0; j < 4; ++j) acc[i][j] = zero4;

  for (int kb = 0; kb < K; kb += 64) {
#pragma unroll
    for (int i = 0; i < 4; ++i) {
      int cbase = w * 256 + i * 64;
      int c = cbase + lane;
      int row = c >> 3;
      int kc8 = ((c & 7) ^ (row & 7)) * 8;
      async16(&Al[cbase * 8], A + (size_t)(mbase + row) * K + kb + kc8);
      async16(&Bl[cbase * 8], Bt + (size_t)(nbase + row) * K + kb + kc8);
    }
    __syncthreads();
#pragma unroll
    for (int ks = 0; ks < 2; ++ks) {
      short8 af[4], bf[4];
#pragma unroll
      for (int mt = 0; mt < 4; ++mt)
        af[mt] = *(const short8*)&Al[(wm + mt * 16 + l15) * 64 + ((ks * 4 + g) ^ sw) * 8];
#pragma unroll
      for (int nt = 0; nt < 4; ++nt)
        bf[nt] = *(const short8*)&Bl[(wn + nt * 16 + l15) * 64 + ((ks * 4 + g) ^ sw) * 8];
      if (ct) {
#pragma unroll
        for (int nt = 0; nt < 4; ++nt)
#pragma unroll
          for (int mt = 0; mt < 4; ++mt)
            acc[nt][mt] = __builtin_amdgcn_mfma_f32_16x16x32_bf16(bf[nt], af[mt],
                                                                  acc[nt][mt], 0, 0, 0);
      } else {
#pragma unroll
        for (int mt = 0; mt < 4; ++mt)
#pragma unroll
          for (int nt = 0; nt < 4; ++nt)
            acc[mt][nt] = __builtin_amdgcn_mfma_f32_16x16x32_bf16(af[mt], bf[nt],
                                                                  acc[mt][nt], 0, 0, 0);
      }
    }
    __syncthreads();
  }

  if (ct) {
#pragma unroll
    for (int mt = 0; mt < 4; ++mt) {
      int m = mbase + wm + mt * 16 + l15;
#pragma unroll
      for (int nt = 0; nt < 4; ++nt)
#pragma unroll
        for (int r = 0; r < 4; ++r) {
          int n = nbase + wn + nt * 16 + g * 4 + r;
          VT[(size_t)n * M + m] = f2bf(acc[nt][mt][r] + bias[n]);
        }
    }
  } else {
#pragma unroll
    for (int nt = 0; nt < 4; ++nt) {
      int col = nbase + wn + nt * 16 + l15;
      float bvv = bias[col];
#pragma unroll
      for (int mt = 0; mt < 4; ++mt)
#pragma unroll
        for (int r = 0; r < 4; ++r) {
          int row = mbase + wm + mt * 16 + g * 4 + r;
          Kp[(size_t)row * N + col] = f2bf(acc[mt][nt][r] + bvv);
        }
    }
  }
}

// ---------------------------------------------------------------------------
// Fused flash attention, S^T/O^T orientation, no-max softmax, MFMA row-sum.
// In-register P (cvt_pk + permlane32/16_swap), no P_lds. LDS 40KB (K 2-buf,
// V 3-buf), single barrier per iteration. 1D grid (2048) with XCD-chunked
// swizzle: same-(b,h) blocks contiguous per XCD for K/V L2 reuse.
// ---------------------------------------------------------------------------
__global__ __launch_bounds__(256, 4) void attn_kernel(const u16* __restrict__ Qp,
                                                      const u16* __restrict__ Kp,
                                                      const u16* __restrict__ VT,
                                                      u16* __restrict__ AO) {
  __shared__ __align__(16) u16 K_lds[2][64 * 64];     // [buf][kcol][d] swizzled
  __shared__ __align__(16) u16 V_lds[3][64 * 64];     // [buf][d][kcol] swizzled

  const int tid = threadIdx.x;
  const int w = tid >> 6, lane = tid & 63;
  const int g = lane >> 4, l15 = lane & 15;
  const int sw = l15 & 7;
  // XCD-chunked swizzle: 2048 blocks, 256/XCD; same-(b,h) 32 blocks adjacent
  const int bid = blockIdx.x;
  const int swzb = (bid & 7) * 256 + (bid >> 3);
  const int bh = swzb >> 5, qblk = swzb & 31;
  const int b = bh >> 4, h = bh & 15;
  const int qrow0 = qblk * 128 + w * 32;
  const int MT = B_SZ * NK;  // VT leading dim
  const int NT4 = NK / 64;   // 16 K/V tiles

  // ---- staging lane constants (two 64-chunk regions per wave) ----
  const int cbase0 = (w * 2 + 0) * 64;
  const int cbase1 = (w * 2 + 1) * 64;
  const int c0 = cbase0 + lane, c1 = cbase1 + lane;
  const int row0 = c0 >> 3, kc80 = ((c0 & 7) ^ (row0 & 7)) * 8;
  const int row1 = c1 >> 3, kc81 = ((c1 & 7) ^ (row1 & 7)) * 8;

  const u16* kp0 = Kp + (size_t)(b * NK + row0) * QDIM + h * HD + kc80;
  const u16* kp1 = Kp + (size_t)(b * NK + row1) * QDIM + h * HD + kc81;
  const u16* vp0 = VT + (size_t)(h * HD + row0) * MT + b * NK + kc80;
  const u16* vp1 = VT + (size_t)(h * HD + row1) * MT + b * NK + kc81;

  // ---- compute lane constants ----
  const int rb = l15 * 64;                      // fragment row base (elements)
  const int cs0 = (g ^ sw) * 8;                 // ks=0 chunk select
  const int cs1 = ((4 + g) ^ sw) * 8;           // ks=1 chunk select

  // ones A-fragment (bf16 1.0 in every slot) for the MFMA row-sum
  short8 ones8;
#pragma unroll
  for (int j = 0; j < 8; ++j) ones8[j] = (short)0x3F80;

  // Q fragments (B-operand role): lane holds Q[qrow=qt*16+l15][d=ks*32+g*8+j]
  short8 qf[2][2];
#pragma unroll
  for (int qt = 0; qt < 2; ++qt)
#pragma unroll
    for (int ks = 0; ks < 2; ++ks) {
      size_t row = (size_t)(b * NQ + qrow0 + qt * 16 + l15);
      qf[qt][ks] = *(const short8*)(Qp + row * QDIM + h * HD + ks * 32 + g * 8);
    }

  f32x4 zero4 = {0.f, 0.f, 0.f, 0.f};
  f32x4 o4[4][2];              // O^T frags: [dt][qt], r-index = d
  f32x4 lacc[2];               // row-sum via mfma(ones, P)
#pragma unroll
  for (int dt = 0; dt < 4; ++dt)
#pragma unroll
    for (int qt = 0; qt < 2; ++qt) o4[dt][qt] = zero4;
  lacc[0] = zero4; lacc[1] = zero4;

  short8 pr[2][2];             // in-register P fragments [ks][qt]:
                               // lane holds P[kcol=ks*32+g*8+j][qrow=l15]

  // exp + cvt_pk + permlane redistribution: sc -> pr.
  // sc[mt][qt][r] = P[kcol=mt*16+g*4+r][qrow=qt*16+l15]. Dest fragment
  // (B-operand): lane(g,l15) elem j = P[kcol=ks*32+g*8+j][qrow]. Quarters:
  // A=[E0..E3] (mt=2ks packed pairs), B=[F0..F3] (mt=2ks+1).
  // P32(A,B): A[32:63]<->B[0:31] -> A=[E0,E1,F0,F1], B=[E2,E3,F2,F3].
  // P16(A,B): A[16:31,48:63]<->B[0:15,32:47] -> A=[E0,E2,F0,F2]=dword0/1,
  // B=[E1,E3,F1,F3]=dword2/3. (LLVM-documented gfx950 semantics.)
  auto packP = [&](const f32x4 (&sc)[4][2], short8 (&prr)[2][2]) {
#pragma unroll
    for (int qt = 0; qt < 2; ++qt)
#pragma unroll
      for (int ks = 0; ks < 2; ++ks) {
        uint32_t A0 = pk2(fexp2(sc[2 * ks][qt][0]), fexp2(sc[2 * ks][qt][1]));
        uint32_t A1 = pk2(fexp2(sc[2 * ks][qt][2]), fexp2(sc[2 * ks][qt][3]));
        uint32_t B0 = pk2(fexp2(sc[2 * ks + 1][qt][0]), fexp2(sc[2 * ks + 1][qt][1]));
        uint32_t B1 = pk2(fexp2(sc[2 * ks + 1][qt][2]), fexp2(sc[2 * ks + 1][qt][3]));
        asm volatile("v_permlane32_swap_b32 %0, %1" : "+v"(A0), "+v"(B0));
        asm volatile("v_permlane32_swap_b32 %0, %1" : "+v"(A1), "+v"(B1));
        asm volatile("v_permlane16_swap_b32 %0, %1" : "+v"(A0), "+v"(B0));
        asm volatile("v_permlane16_swap_b32 %0, %1" : "+v"(A1), "+v"(B1));
        union { uint32_t u[4]; short8 s; } wd;
        wd.u[0] = A0; wd.u[1] = A1; wd.u[2] = B0; wd.u[3] = B1;
        prr[ks][qt] = wd.s;
      }
  };

  // ---- prologue: stage tile 0 (K[0],V[0]); then tile 1 (K[1],V[1]) ----
  async16(&K_lds[0][cbase0 * 8], kp0);
  async16(&K_lds[0][cbase1 * 8], kp1);
  async16(&V_lds[0][cbase0 * 8], vp0);
  async16(&V_lds[0][cbase1 * 8], vp1);
  kp0 += 64 * QDIM; kp1 += 64 * QDIM; vp0 += 64; vp1 += 64;
  __syncthreads();  // tile 0 resident

  async16(&K_lds[1][cbase0 * 8], kp0);
  async16(&K_lds[1][cbase1 * 8], kp1);
  async16(&V_lds[1][cbase0 * 8], vp0);
  async16(&V_lds[1][cbase1 * 8], vp1);
  kp0 += 64 * QDIM; kp1 += 64 * QDIM; vp0 += 64; vp1 += 64;

  // QK^T(0) + exp -> pr(0)
  {
    const u16* Kl = &K_lds[0][0];
    f32x4 sc[4][2];
    short8 kf0[4], kf1[4];
#pragma unroll
    for (int mt = 0; mt < 4; ++mt) {
      kf0[mt] = *(const short8*)&Kl[mt * 1024 + rb + cs0];
      kf1[mt] = *(const short8*)&Kl[mt * 1024 + rb + cs1];
    }
    __builtin_amdgcn_s_setprio(1);
#pragma unroll
    for (int mt = 0; mt < 4; ++mt)
#pragma unroll
      for (int qt = 0; qt < 2; ++qt)
        sc[mt][qt] = __builtin_amdgcn_mfma_f32_16x16x32_bf16(kf0[mt], qf[qt][0],
                                                             zero4, 0, 0, 0);
#pragma unroll
    for (int mt = 0; mt < 4; ++mt)
#pragma unroll
      for (int qt = 0; qt < 2; ++qt)
        sc[mt][qt] = __builtin_amdgcn_mfma_f32_16x16x32_bf16(kf1[mt], qf[qt][1],
                                                             sc[mt][qt], 0, 0, 0);
    __builtin_amdgcn_s_setprio(0);
    packP(sc, pr);
  }
  __syncthreads();  // tile 1 resident

  // ---- main loop: QK^T(kc) ++ PV(kc-1), then exp->pr(kc) ----
  for (int kc = 1; kc < NT4; ++kc) {
    // stage tile kc+1: K into (kc+1)&1 (holds K(kc-1), dead), V into
    // (kc+1)%3 (holds V(kc-2), dead since iteration kc-1).
    if (kc + 1 < NT4) {
      const int nk = (kc + 1) & 1, nv = (kc + 1) % 3;
      async16(&K_lds[nk][cbase0 * 8], kp0);
      async16(&K_lds[nk][cbase1 * 8], kp1);
      async16(&V_lds[nv][cbase0 * 8], vp0);
      async16(&V_lds[nv][cbase1 * 8], vp1);
      kp0 += 64 * QDIM; kp1 += 64 * QDIM; vp0 += 64; vp1 += 64;
    }
    const u16* Kl = &K_lds[kc & 1][0];
    const u16* Vl = &V_lds[(kc - 1) % 3][0];

    // fragment loads: vf feeds PV(kc-1), kf feeds QK^T(kc)
    short8 vf[2][4], kf[2][4];
#pragma unroll
    for (int dt = 0; dt < 4; ++dt) {
      vf[0][dt] = *(const short8*)&Vl[dt * 1024 + rb + cs0];
      vf[1][dt] = *(const short8*)&Vl[dt * 1024 + rb + cs1];
    }
#pragma unroll
    for (int mt = 0; mt < 4; ++mt) {
      kf[0][mt] = *(const short8*)&Kl[mt * 1024 + rb + cs0];
      kf[1][mt] = *(const short8*)&Kl[mt * 1024 + rb + cs1];
    }

    // merged MFMA cluster: QK^T(kc) and PV(kc-1) are independent
    f32x4 sc[4][2];
    __builtin_amdgcn_s_setprio(1);
#pragma unroll
    for (int mt = 0; mt < 4; ++mt)
#pragma unroll
      for (int qt = 0; qt < 2; ++qt)
        sc[mt][qt] = __builtin_amdgcn_mfma_f32_16x16x32_bf16(kf[0][mt], qf[qt][0],
                                                             zero4, 0, 0, 0);
#pragma unroll
    for (int qt = 0; qt < 2; ++qt)
      lacc[qt] = __builtin_amdgcn_mfma_f32_16x16x32_bf16(ones8, pr[0][qt],
                                                         lacc[qt], 0, 0, 0);
#pragma unroll
    for (int dt = 0; dt < 4; ++dt)
#pragma unroll
      for (int qt = 0; qt < 2; ++qt)
        o4[dt][qt] = __builtin_amdgcn_mfma_f32_16x16x32_bf16(vf[0][dt], pr[0][qt],
                                                             o4[dt][qt], 0, 0, 0);
#pragma unroll
    for (int mt = 0; mt < 4; ++mt)
#pragma unroll
      for (int qt = 0; qt < 2; ++qt)
        sc[mt][qt] = __builtin_amdgcn_mfma_f32_16x16x32_bf16(kf[1][mt], qf[qt][1],
                                                             sc[mt][qt], 0, 0, 0);
#pragma unroll
    for (int qt = 0; qt < 2; ++qt)
      lacc[qt] = __builtin_amdgcn_mfma_f32_16x16x32_bf16(ones8, pr[1][qt],
                                                         lacc[qt], 0, 0, 0);
#pragma unroll
    for (int dt = 0; dt < 4; ++dt)
#pragma unroll
      for (int qt = 0; qt < 2; ++qt)
        o4[dt][qt] = __builtin_amdgcn_mfma_f32_16x16x32_bf16(vf[1][dt], pr[1][qt],
                                                             o4[dt][qt], 0, 0, 0);
    __builtin_amdgcn_s_setprio(0);

    // exp(kc) -> pr (registers; overwrites pr(kc-1), already consumed)
    packP(sc, pr);

    if (kc + 1 < NT4) __syncthreads();  // staged tile resident next iteration
  }

  // ---- epilogue: PV for the last tile, V slot (NT4-1)%3 ----
  {
    const u16* Vl = &V_lds[(NT4 - 1) % 3][0];
    short8 vf[2][4];
#pragma unroll
    for (int dt = 0; dt < 4; ++dt) {
      vf[0][dt] = *(const short8*)&Vl[dt * 1024 + rb + cs0];
      vf[1][dt] = *(const short8*)&Vl[dt * 1024 + rb + cs1];
    }
    __builtin_amdgcn_s_setprio(1);
#pragma unroll
    for (int ks = 0; ks < 2; ++ks) {
#pragma unroll
      for (int qt = 0; qt < 2; ++qt)
        lacc[qt] = __builtin_amdgcn_mfma_f32_16x16x32_bf16(ones8, pr[ks][qt],
                                                           lacc[qt], 0, 0, 0);
#pragma unroll
      for (int dt = 0; dt < 4; ++dt)
#pragma unroll
        for (int qt = 0; qt < 2; ++qt)
          o4[dt][qt] = __builtin_amdgcn_mfma_f32_16x16x32_bf16(vf[ks][dt], pr[ks][qt],
                                                               o4[dt][qt], 0, 0, 0);
    }
    __builtin_amdgcn_s_setprio(0);
  }

  // epilogue: lacc[qt][r] all hold the full row-sum for qrow=qt*16+l15
#pragma unroll
  for (int qt = 0; qt < 2; ++qt) {
    float inv = __builtin_amdgcn_rcpf(lacc[qt][0]);
    size_t row = (size_t)(b * NQ + qrow0 + qt * 16 + l15);
#pragma unroll
    for (int dt = 0; dt < 4; ++dt) {
      uint2 pk = {pk2(o4[dt][qt][0] * inv, o4[dt][qt][1] * inv),
                  pk2(o4[dt][qt][2] * inv, o4[dt][qt][3] * inv)};
      *(uint2*)(AO + row * QDIM + h * HD + dt * 16 + g * 4) = pk;
    }
  }
}

// ---------------------------------------------------------------------------
extern "C" void kernel_launch(void* const* d_in, const int* in_sizes, int n_in,
                              void* d_out, int out_size, void* d_ws, size_t ws_size,
                              hipStream_t stream) {
  const float* query = (const float*)d_in[0];
  const float* key   = (const float*)d_in[1];
  const float* value = (const float*)d_in[2];
  const float* Wq = (const float*)d_in[3];
  const float* bq = (const float*)d_in[4];
  const float* Wk = (const float*)d_in[5];
  const float* bk = (const float*)d_in[6];
  const float* Wv = (const float*)d_in[7];
  const float* bv = (const float*)d_in[8];
  const float* Wo = (const float*)d_in[9];
  const float* bo = (const float*)d_in[10];

  char* ws = (char*)d_ws;
  size_t off = 0;
  auto alloc = [&](size_t bytes) -> void* {
    void* p = ws + off;
    off += (bytes + 255) & ~(size_t)255;
    return p;
  };
  const size_t NQTOT = (size_t)B_SZ * NQ;        // 16384
  const size_t NKTOT = (size_t)B_SZ * NK;        // 4096
  u16* qbf = (u16*)alloc(NQTOT * QDIM * 2);      // query bf16; reused as AO later
  u16* kbf = (u16*)alloc(NKTOT * KDIM * 2);
  u16* vbf = (u16*)alloc(NKTOT * KDIM * 2);
  u16* wqt = (u16*)alloc((size_t)QDIM * QDIM * 2);
  u16* wkt = (u16*)alloc((size_t)KDIM * QDIM * 2);
  u16* wvt = (u16*)alloc((size_t)KDIM * QDIM * 2);
  u16* wot = (u16*)alloc((size_t)QDIM * QDIM * 2);
  u16* Qp  = (u16*)alloc(NQTOT * QDIM * 2);
  u16* Kp  = (u16*)alloc(NKTOT * QDIM * 2);
  u16* VT  = (u16*)alloc((size_t)QDIM * NKTOT * 2);  // (1024, B*NK) transposed V-proj
  u16* AO  = qbf;  // qbf dead after Q-projection

  // 1) dtype conversions: all three tensors in ONE launch
  {
    int n4q  = (int)(NQTOT * QDIM / 4);   // 4,194,304
    int n4kv = (int)(NKTOT * KDIM / 4);   //   786,432
    int nb = (n4q + 2 * n4kv + 255) / 256;
    f32_to_bf16_all<<<nb, 256, 0, stream>>>(query, key, value, qbf, kbf, vbf,
                                            n4q, n4kv);
  }
  // 2) weight transposes: all four in ONE launch (z selects)
  transpose4_k<<<dim3(QDIM / 32, QDIM / 32, 4), 256, 0, stream>>>(
      Wq, Wk, Wv, Wo, wqt, wkt, wvt, wot);

  // 3) projections: Q scaled by QSCALE (softmax exp2-domain fold); K+V fused
  gemm_bt256<<<(NQTOT / 128) * (QDIM / 256), 512, 0, stream>>>(
      qbf, wqt, bq, nullptr, Qp, (int)NQTOT, QDIM, QDIM, 1, QSCALE);
  gemm_kv<<<(NKTOT / 128) * (QDIM / 128) * 2, 256, 0, stream>>>(
      kbf, vbf, wkt, wvt, bk, bv, Kp, VT, (int)NKTOT, QDIM, KDIM);

  // 4) fused attention -> AO (bf16, (B*Nq, 1024)); 1D grid, XCD-swizzled
  attn_kernel<<<(NQ / 128) * (B_SZ * NH), 256, 0, stream>>>(Qp, Kp, VT, AO);

  // 5) output projection (fp32 out)
  gemm_bt256<<<(NQTOT / 128) * (QDIM / 256), 512, 0, stream>>>(
      AO, wot, bo, (float*)d_out, nullptr, (int)NQTOT, QDIM, QDIM, 0, 1.0f);

  (void)in_sizes; (void)n_in; (void)out_size; (void)ws_size;
}